// Round 2
// baseline (423.102 us; speedup 1.0000x reference)
//
#include <hip/hip_runtime.h>

// SmartDerivatives R10: R8's staging + uniform chunk-mapped consumption,
// single kernel, no ws round-trip.
//
// R9 post-mortem: per-float2 class routing diverges within every wave
// (3 serialized branch bodies/pair) + dependent x gathers -> latency-bound,
// VALUBusy 19%, HBM 8%. R8's stage was fine; its compute phase was the
// problem (390/1024 threads, ~230-slot critical path, ws+combine).
//
// R10: stage z = left*x into LDS exactly like R8 (two halves per frame,
// float4-coalesced, 2 blocks/CU so stage(B) overlaps compute(A)). Consume
// with a constexpr thread->chunk map: each thread owns 3 consecutive descs
// of ONE row (1683 chunks: 831 half0 / 852 half1). Per desc: 3 ds_read_b64
// (imm offsets, 4-way bank alias), 3 reg adds (row ch), 3 ds_add (col ch,
// conflict-free); 3 ds_add row-flush per thread. All into acc[300] in LDS;
// square + write out directly. Critical path ~50 slots on ~83% of threads.

#define D_DESC  4950
#define BATCH   1024
#define NOUT    300

// half 0: rows 0..28,  descs [0,2465),    float4 [0,3698)     zb=0
// half 1: rows 29..98, descs [2465,4950), float4 [3697,7425)  zb=14788
#define F4_MAX  3728

struct MapT { unsigned v[1700]; int n0; int ntot; };

constexpr MapT build_map() {
    MapT m{};
    int idx = 0, n0 = 0;
    for (int a = 0; a < 99; ++a) {
        const int len = 99 - a;
        const int rs  = (a * (199 - a)) / 2;
        for (int m0 = 0; m0 < len; m0 += 3) {
            const int ml = (len - m0 < 3) ? (len - m0) : 3;
            m.v[idx++] = (unsigned)a | ((unsigned)m0 << 7) |
                         ((unsigned)ml << 14) | ((unsigned)rs << 17);
        }
        if (a == 28) n0 = idx;
    }
    m.n0 = n0; m.ntot = idx;
    return m;
}

constexpr MapT MAP_CPU = build_map();
__device__ const MapT MAP = MAP_CPU;          // .rodata, static-init
constexpr int NH[2]   = {MAP_CPU.n0, MAP_CPU.ntot - MAP_CPU.n0};   // 831, 852
constexpr int OFFH[2] = {0, MAP_CPU.n0};

__global__ __launch_bounds__(1024, 8)
void sd_kernel(const float* __restrict__ x,
               const float* __restrict__ left,
               float* __restrict__ out)
{
    __shared__ float4 sz4[F4_MAX];
    __shared__ __align__(16) float acc[NOUT];

    const int b   = blockIdx.x;
    const int tid = threadIdx.x;

    if (tid < NOUT) acc[tid] = 0.0f;

    const float* __restrict__ xb = x + (size_t)b * D_DESC;
    const float* sz = (const float*)sz4;

    #pragma unroll
    for (int h = 0; h < 2; ++h) {
        const int f4start = h ? 3697 : 0;
        const int f4cnt   = h ? 3728 : 3698;
        const int zb      = f4start * 4;
        const float4* __restrict__ lb4 =
            (const float4*)(left + (size_t)b * (D_DESC * 6)) + f4start;

        // ---- stage z = left * x (dense float4 loads; x from L1/L2).
        // float4 idx covers frame floats g..g+3; r = g%6 in {0,2,4}; only
        // r==4 straddles two descriptors (elements 2,3 -> d0+1).
        #pragma unroll
        for (int k = 0; k < 4; ++k) {
            const int idx = tid + k * 1024;
            if (idx < f4cnt) {
                const float4 L = lb4[idx];
                const int g  = (f4start + idx) * 4;
                const int d0 = g / 6;
                const int r  = g - 6 * d0;
                const float x0 = xb[d0];
                const float x1 = xb[(g + 3) / 6];   // == x0 unless r==4
                float4 z;
                z.x = L.x * x0;
                z.y = L.y * x0;
                z.z = L.z * ((r + 2 >= 6) ? x1 : x0);
                z.w = L.w * ((r + 3 >= 6) ? x1 : x0);
                sz4[idx] = z;
            }
        }
        __syncthreads();   // tile ready (and acc zeroed, h==0)

        // ---- consume: thread -> (row a, 3-desc chunk at m0)
        if (tid < NH[h]) {
            const unsigned e = MAP.v[OFFH[h] + tid];
            const int a  = e & 127;
            const int m0 = (e >> 7) & 127;
            const int ml = (e >> 14) & 7;
            const int rs = (int)(e >> 17);
            const float* __restrict__ p = sz + ((rs + m0) * 6 - zb);
            const int j3 = (a + 1 + m0) * 3;
            float s0 = 0.f, s1 = 0.f, s2 = 0.f;
            #pragma unroll
            for (int mi = 0; mi < 3; ++mi) {
                if (mi < ml) {
                    const float2 c01 = *(const float2*)(p + mi * 6);
                    const float2 c23 = *(const float2*)(p + mi * 6 + 2);
                    const float2 c45 = *(const float2*)(p + mi * 6 + 4);
                    s0 += c01.x; s1 += c01.y; s2 += c23.x;
                    atomicAdd(&acc[j3 + mi * 3 + 0], c23.y);
                    atomicAdd(&acc[j3 + mi * 3 + 1], c45.x);
                    atomicAdd(&acc[j3 + mi * 3 + 2], c45.y);
                }
            }
            atomicAdd(&acc[a * 3 + 0], s0);
            atomicAdd(&acc[a * 3 + 1], s1);
            atomicAdd(&acc[a * 3 + 2], s2);
        }
        __syncthreads();   // tile consumed (next half may overwrite) / acc final
    }

    // ---- out[b, :] = acc^2, float4-vectorized (300 = 75 * 4, 16B-aligned)
    if (tid < NOUT / 4) {
        const float4 v = ((const float4*)acc)[tid];
        float4 o;
        o.x = v.x * v.x; o.y = v.y * v.y;
        o.z = v.z * v.z; o.w = v.w * v.w;
        ((float4*)(out + (size_t)b * NOUT))[tid] = o;
    }
}

extern "C" void kernel_launch(void* const* d_in, const int* in_sizes, int n_in,
                              void* d_out, int out_size, void* d_ws, size_t ws_size,
                              hipStream_t stream) {
    (void)in_sizes; (void)n_in; (void)d_ws; (void)ws_size; (void)out_size;
    const float* x    = (const float*)d_in[0];   // [BATCH, D]
    const float* left = (const float*)d_in[1];   // [BATCH*D*6]
    sd_kernel<<<BATCH, 1024, 0, stream>>>(x, left, (float*)d_out);
}

// Round 3
// 339.410 us; speedup vs baseline: 1.2466x; 1.2466x over previous
//
#include <hip/hip_runtime.h>

// SmartDerivatives R11: streaming, atomic-free, barrier-free main loop.
//
// R10 post-mortem: LDS atomicAdd volume is the poison (R8 no-atomics 51us,
// R9 15K atomics/frame 114us, R10 20K/frame 148us; VALUBusy 3% = issue
// starvation, not BW). Also: 61KB LDS -> 2 blocks/CU -> every stage latency
// exposed behind full-block barriers.
//
// R11: one block (8 waves, 512 thr) per frame. Wave w owns rows {w, w+8,...};
// lane l owns descriptors d = l + 64m of that row. Within a row every d has a
// DISTINCT column j = a+1+d, so the column scatter has no same-address
// collision within any instruction; cacc is PER-WAVE private -> non-atomic
// ds_read_b128 / 3 fadds / ds_write_b128, ordered by the wave's in-order DS
// pipe. Row channels (0..2) accumulate in registers, one shuffle-reduce per
// row (levels skipped when len is short), single-writer store to racc[a].
// No staging tile: left streamed as 3 coalesced float2/desc, x gathered
// coalesced (d lane-contiguous). LDS 14.4KB -> wave-limited 4 blocks/CU,
// grid 1024 = one residency round, zero barriers before the epilogue.

#define D_DESC 4950
#define BATCH  1024
#define NOUT   300
#define NW     8       // waves per block (512 threads)

__device__ __forceinline__ int rowstart(int i) { return (i * (199 - i)) >> 1; }

__global__ __launch_bounds__(512, 8)
void sd_kernel(const float* __restrict__ x,
               const float* __restrict__ left,
               float* __restrict__ out)
{
    __shared__ float4 cacc[NW * 100];   // [wave][atom]: col channels 3..5
    __shared__ float4 racc[100];        // [atom]: row channels 0..2, 1 writer

    const int b    = blockIdx.x;
    const int tid  = threadIdx.x;
    const int lane = tid & 63;
    const int w    = tid >> 6;

    // zero own wave's cacc slice — same-wave DS ordering makes it visible
    // to this wave's later RMW without any barrier.
    for (int t = lane; t < 100; t += 64)
        cacc[w * 100 + t] = float4{0.f, 0.f, 0.f, 0.f};
    if (tid == 0) racc[99] = float4{0.f, 0.f, 0.f, 0.f};  // atom 99: no row part

    const float* __restrict__ Lb = left + (size_t)b * (D_DESC * 6);
    const float* __restrict__ xb = x    + (size_t)b * D_DESC;

    for (int a = w; a < 99; a += NW) {
        const int len = 99 - a;               // descs in row a
        const int rs  = rowstart(a);
        const float* __restrict__ base = Lb + rs * 6;   // 8B-aligned
        float s0 = 0.f, s1 = 0.f, s2 = 0.f;

        for (int d0 = 0; d0 < len; d0 += 64) {
            const int d = d0 + lane;
            if (d < len) {
                const float2 c01 = *(const float2*)(base + d * 6);
                const float2 c23 = *(const float2*)(base + d * 6 + 2);
                const float2 c45 = *(const float2*)(base + d * 6 + 4);
                const float xv = xb[rs + d];          // coalesced gather
                s0 += c01.x * xv;
                s1 += c01.y * xv;
                s2 += c23.x * xv;
                // col scatter: j distinct per active lane, wave-private slot
                float4* slot = &cacc[w * 100 + (a + 1 + d)];
                float4 cur = *slot;                   // ds_read_b128
                cur.x += c23.y * xv;
                cur.y += c45.x * xv;
                cur.z += c45.y * xv;
                *slot = cur;                          // ds_write_b128
            }
        }

        // reduce row sums over the lanes that held data (wave-uniform branch)
        const int nact = len < 64 ? len : 64;
        #pragma unroll
        for (int off = 32; off >= 1; off >>= 1) {
            if (nact > off) {
                s0 += __shfl_down(s0, off);
                s1 += __shfl_down(s1, off);
                s2 += __shfl_down(s2, off);
            }
        }
        if (lane == 0) racc[a] = float4{s0, s1, s2, 0.f};
    }
    __syncthreads();

    // out[b, t*3+dim] = (racc[t] + sum_w cacc[w][t])^2
    if (tid < 100) {
        float4 v = racc[tid];
        #pragma unroll
        for (int ww = 0; ww < NW; ++ww) {
            const float4 c = cacc[ww * 100 + tid];
            v.x += c.x; v.y += c.y; v.z += c.z;
        }
        float* __restrict__ o = out + (size_t)b * NOUT + tid * 3;
        o[0] = v.x * v.x;
        o[1] = v.y * v.y;
        o[2] = v.z * v.z;
    }
}

extern "C" void kernel_launch(void* const* d_in, const int* in_sizes, int n_in,
                              void* d_out, int out_size, void* d_ws, size_t ws_size,
                              hipStream_t stream) {
    (void)in_sizes; (void)n_in; (void)d_ws; (void)ws_size; (void)out_size;
    const float* x    = (const float*)d_in[0];   // [BATCH, D]
    const float* left = (const float*)d_in[1];   // [BATCH*D*6]
    sd_kernel<<<BATCH, 512, 0, stream>>>(x, left, (float*)d_out);
}